// Round 1
// baseline (98.974 us; speedup 1.0000x reference)
//
#include <hip/hip_runtime.h>

typedef short short8 __attribute__((ext_vector_type(8)));
typedef float f32x4 __attribute__((ext_vector_type(4)));

#define BM 64
#define BN 128
#define BK 64

__device__ inline unsigned short f2bf(float f) {
  unsigned x = __builtin_bit_cast(unsigned, f);
  x += 0x7fffu + ((x >> 16) & 1u);
  return (unsigned short)(x >> 16);
}

__global__ __launch_bounds__(512, 2) void qgemm_kernel(
    const float* __restrict__ x, const int* __restrict__ qw,
    const int* __restrict__ qz, const float* __restrict__ sc,
    const float* __restrict__ bias, float* __restrict__ out,
    int M, int N, int K) {
  // LDS: As [64 rows][64 k] bf16 (8KB) + Bs [128 n-rows][64 k] bf16 (16KB)
  __shared__ __align__(16) unsigned char smem[BM * BK * 2 + BK * BN * 2];
  const int tid = threadIdx.x;
  const int n0 = blockIdx.x * BN;
  const int m0 = blockIdx.y * BM;
  const int wid = tid >> 6;
  const int lane = tid & 63;
  const int wr = wid >> 2;        // 0..1  (M wave row)
  const int wc = wid & 3;         // 0..3  (N wave col)
  const int lcol = lane & 15;
  const int lk = lane >> 4;
  const int N8 = N >> 3;

  f32x4 acc[2][2] = {};

  // A staging: thread -> (row 0..63, col-group 0..7), 8 fp32 each
  const int arow = tid >> 3;
  const int acg = tid & 7;

  for (int k0 = 0; k0 < K; k0 += BK) {
    // ---- stage A tile (fp32 -> bf16), swizzled [row][k] ----
    {
      const float* src = x + (m0 + arow) * K + k0 + acg * 8;
      float4 v0 = *(const float4*)(src);
      float4 v1 = *(const float4*)(src + 4);
      short8 p;
      p[0] = (short)f2bf(v0.x); p[1] = (short)f2bf(v0.y);
      p[2] = (short)f2bf(v0.z); p[3] = (short)f2bf(v0.w);
      p[4] = (short)f2bf(v1.x); p[5] = (short)f2bf(v1.y);
      p[6] = (short)f2bf(v1.z); p[7] = (short)f2bf(v1.w);
      *(short8*)(smem + arow * 128 + ((acg ^ (arow & 7)) << 4)) = p;
    }
    // ---- stage B tile: dequant int4 -> bf16, [n][k] swizzled ----
    {
      const int g = k0 >> 7;          // GPTQ group (GROUP=128, BK=64 divides it)
      const int kq0 = k0 >> 3;        // packed row base
#pragma unroll
      for (int i = 0; i < 2; ++i) {
        int idx = tid + 512 * i;
        int row8 = idx >> 7;          // 0..7  (8 packed rows = 64 k)
        int col = idx & 127;          // 0..127 (n within tile)
        int gn = n0 + col;
        int v = qw[(kq0 + row8) * N + gn];
        float s = sc[g * N + gn];
        int zv = (qz[g * N8 + (gn >> 3)] >> ((col & 7) * 4)) & 0xF;
        float zp1 = (float)(zv + 1);
        short8 p;
#pragma unroll
        for (int b = 0; b < 8; ++b) {
          float w = s * ((float)((v >> (4 * b)) & 0xF) - zp1);
          p[b] = (short)f2bf(w);
        }
        *(short8*)(smem + 8192 + col * 128 + ((row8 ^ (col & 7)) << 4)) = p;
      }
    }
    __syncthreads();
    // ---- compute: 2 kk-steps x (2m x 2n) mfma 16x16x32 ----
#pragma unroll
    for (int kk = 0; kk < 2; ++kk) {
      short8 a[2], b[2];
      int unit = kk * 4 + lk;
#pragma unroll
      for (int fi = 0; fi < 2; ++fi) {
        int row = wr * 32 + fi * 16 + lcol;
        a[fi] = *(short8*)(smem + row * 128 + ((unit ^ (row & 7)) << 4));
      }
#pragma unroll
      for (int fj = 0; fj < 2; ++fj) {
        int nrow = wc * 32 + fj * 16 + lcol;
        b[fj] = *(short8*)(smem + 8192 + nrow * 128 + ((unit ^ (nrow & 7)) << 4));
      }
#pragma unroll
      for (int fi = 0; fi < 2; ++fi)
#pragma unroll
        for (int fj = 0; fj < 2; ++fj)
          acc[fi][fj] = __builtin_amdgcn_mfma_f32_16x16x32_bf16(
              a[fi], b[fj], acc[fi][fj], 0, 0, 0);
    }
    __syncthreads();
  }

  // ---- epilogue: C/D layout col=lane&15, row=(lane>>4)*4+r ----
#pragma unroll
  for (int fi = 0; fi < 2; ++fi) {
    int gm = m0 + wr * 32 + fi * 16 + lk * 4;
#pragma unroll
    for (int fj = 0; fj < 2; ++fj) {
      int gn = n0 + wc * 32 + fj * 16 + lcol;
      float bv = bias[gn];
#pragma unroll
      for (int r = 0; r < 4; ++r)
        out[(gm + r) * N + gn] = acc[fi][fj][r] + bv;
    }
  }
}

extern "C" void kernel_launch(void* const* d_in, const int* in_sizes, int n_in,
                              void* d_out, int out_size, void* d_ws, size_t ws_size,
                              hipStream_t stream) {
  const float* x = (const float*)d_in[0];
  const int* qw = (const int*)d_in[1];
  const int* qz = (const int*)d_in[2];
  const float* sc = (const float*)d_in[3];
  const float* bias = (const float*)d_in[4];
  float* out = (float*)d_out;

  int N = in_sizes[4];                 // bias: [N]
  int K = (in_sizes[1] / N) * 8;       // qweight: [K/8, N]
  int M = in_sizes[0] / K;             // x: [M, K] flattened

  dim3 grid(N / BN, M / BM);
  qgemm_kernel<<<grid, 512, 0, stream>>>(x, qw, qz, sc, bias, out, M, N, K);
}

// Round 2
// 69.279 us; speedup vs baseline: 1.4286x; 1.4286x over previous
//
#include <hip/hip_runtime.h>

typedef short short8 __attribute__((ext_vector_type(8)));
typedef float f32x4 __attribute__((ext_vector_type(4)));

#define BM 64
#define BN 128
#define BK 64
#define SPLITK 4
#define LDS_HALF (BM * BK * 2 + BK * BN * 2)   // 24576 bytes per buffer

__device__ inline unsigned short f2bf(float f) {
  unsigned x = __builtin_bit_cast(unsigned, f);
  x += 0x7fffu + ((x >> 16) & 1u);
  return (unsigned short)(x >> 16);
}

__global__ void init_out_kernel(const float* __restrict__ bias,
                                float* __restrict__ out, int MN, int N) {
  int i = (blockIdx.x * blockDim.x + threadIdx.x) * 4;
  if (i < MN) {
    *(float4*)(out + i) = *(const float4*)(bias + (i % N));
  }
}

__global__ __launch_bounds__(512, 2) void qgemm_kernel(
    const float* __restrict__ x, const int* __restrict__ qw,
    const int* __restrict__ qz, const float* __restrict__ sc,
    float* __restrict__ out, int M, int N, int K) {
  __shared__ __align__(16) unsigned char smem[2 * LDS_HALF];  // 48 KB
  const int tid = threadIdx.x;
  const int n0 = blockIdx.x * BN;
  const int m0 = blockIdx.y * BM;
  const int KC = K / SPLITK;
  const int kbase = blockIdx.z * KC;
  const int nt = KC / BK;
  const int wid = tid >> 6;
  const int lane = tid & 63;
  const int wr = wid >> 2;   // 0..1
  const int wc = wid & 3;    // 0..3
  const int lcol = lane & 15;
  const int lk = lane >> 4;
  const int N8 = N >> 3;

  f32x4 acc[2][2] = {};

  // A staging map: thread -> (row 0..63, col-group 0..7), 8 fp32
  const int arow = tid >> 3;
  const int acg = tid & 7;
  // B staging map: thread -> (col 0..127, packed rows {r, r+4}), r = tid>>7
  const int bcol = tid & 127;
  const int brow8 = tid >> 7;   // 0..3
  const int gn = n0 + bcol;

  // prefetch registers
  float4 pa0, pa1;
  int pw0, pw1;
  float pbs, pbzp;

  auto LOAD = [&](int t) {
    int k0 = kbase + t * BK;
    const float* src = x + (m0 + arow) * K + k0 + acg * 8;
    pa0 = *(const float4*)(src);
    pa1 = *(const float4*)(src + 4);
    int g = k0 >> 7;
    int kq0 = k0 >> 3;
    pw0 = qw[(kq0 + brow8) * N + gn];
    pw1 = qw[(kq0 + brow8 + 4) * N + gn];
    pbs = sc[g * N + gn];
    int zv = (qz[g * N8 + (gn >> 3)] >> ((bcol & 7) * 4)) & 0xF;
    pbzp = (float)(zv + 1);
  };

  auto STORE = [&](int buf) {
    unsigned char* base = smem + buf * LDS_HALF;
    short8 p;
    p[0] = (short)f2bf(pa0.x); p[1] = (short)f2bf(pa0.y);
    p[2] = (short)f2bf(pa0.z); p[3] = (short)f2bf(pa0.w);
    p[4] = (short)f2bf(pa1.x); p[5] = (short)f2bf(pa1.y);
    p[6] = (short)f2bf(pa1.z); p[7] = (short)f2bf(pa1.w);
    *(short8*)(base + arow * 128 + ((acg ^ (arow & 7)) << 4)) = p;

    unsigned char* bb = base + 8192;
    short8 q0, q1;
#pragma unroll
    for (int b = 0; b < 8; ++b) {
      q0[b] = (short)f2bf(pbs * ((float)((pw0 >> (4 * b)) & 0xF) - pbzp));
      q1[b] = (short)f2bf(pbs * ((float)((pw1 >> (4 * b)) & 0xF) - pbzp));
    }
    *(short8*)(bb + bcol * 128 + ((brow8 ^ (bcol & 7)) << 4)) = q0;
    *(short8*)(bb + bcol * 128 + (((brow8 + 4) ^ (bcol & 7)) << 4)) = q1;
  };

  auto COMPUTE = [&](int buf) {
    unsigned char* base = smem + buf * LDS_HALF;
    unsigned char* bb = base + 8192;
#pragma unroll
    for (int kk = 0; kk < 2; ++kk) {
      short8 a[2], b[2];
      int unit = kk * 4 + lk;
#pragma unroll
      for (int fi = 0; fi < 2; ++fi) {
        int row = wr * 32 + fi * 16 + lcol;
        a[fi] = *(short8*)(base + row * 128 + ((unit ^ (row & 7)) << 4));
      }
#pragma unroll
      for (int fj = 0; fj < 2; ++fj) {
        int nrow = wc * 32 + fj * 16 + lcol;
        b[fj] = *(short8*)(bb + nrow * 128 + ((unit ^ (nrow & 7)) << 4));
      }
#pragma unroll
      for (int fi = 0; fi < 2; ++fi)
#pragma unroll
        for (int fj = 0; fj < 2; ++fj)
          acc[fi][fj] = __builtin_amdgcn_mfma_f32_16x16x32_bf16(
              a[fi], b[fj], acc[fi][fj], 0, 0, 0);
    }
  };

  // prologue
  LOAD(0);
  STORE(0);
  __syncthreads();

  for (int t = 0; t < nt; ++t) {
    int cur = t & 1;
    if (t + 1 < nt) LOAD(t + 1);     // issue global loads early
    COMPUTE(cur);                     // hide latency under ds_read+MFMA
    if (t + 1 < nt) STORE(cur ^ 1);  // land prefetch in other buffer
    __syncthreads();
  }

  // epilogue: atomic-accumulate split-K partials (bias pre-written by init)
#pragma unroll
  for (int fi = 0; fi < 2; ++fi) {
    int gm = m0 + wr * 32 + fi * 16 + lk * 4;
#pragma unroll
    for (int fj = 0; fj < 2; ++fj) {
      int gc = n0 + wc * 32 + fj * 16 + lcol;
#pragma unroll
      for (int r = 0; r < 4; ++r)
        unsafeAtomicAdd(&out[(gm + r) * N + gc], acc[fi][fj][r]);
    }
  }
}

extern "C" void kernel_launch(void* const* d_in, const int* in_sizes, int n_in,
                              void* d_out, int out_size, void* d_ws, size_t ws_size,
                              hipStream_t stream) {
  const float* x = (const float*)d_in[0];
  const int* qw = (const int*)d_in[1];
  const int* qz = (const int*)d_in[2];
  const float* sc = (const float*)d_in[3];
  const float* bias = (const float*)d_in[4];
  float* out = (float*)d_out;

  int N = in_sizes[4];
  int K = (in_sizes[1] / N) * 8;
  int M = in_sizes[0] / K;
  int MN = M * N;

  init_out_kernel<<<(MN / 4 + 255) / 256, 256, 0, stream>>>(bias, out, MN, N);

  dim3 grid(N / BN, M / BM, SPLITK);
  qgemm_kernel<<<grid, 512, 0, stream>>>(x, qw, qz, sc, out, M, N, K);
}

// Round 4
// 66.249 us; speedup vs baseline: 1.4940x; 1.0457x over previous
//
#include <hip/hip_runtime.h>
#include <hip/hip_fp16.h>

typedef _Float16 half8 __attribute__((ext_vector_type(8)));
typedef _Float16 half2v __attribute__((ext_vector_type(2)));
typedef float f32x4 __attribute__((ext_vector_type(4)));

#define BM 64
#define BN 128
#define BK 64
#define SPLITK 8
#define LDS_HALF (BM * BK * 2 + BK * BN * 2)   // 24576 bytes per buffer

__device__ inline unsigned pkrtz(float lo, float hi) {
  return __builtin_bit_cast(unsigned, __builtin_amdgcn_cvt_pkrtz(lo, hi));
}

__global__ void init_out_kernel(const float* __restrict__ bias,
                                float* __restrict__ out, int MN, int N) {
  int i = (blockIdx.x * blockDim.x + threadIdx.x) * 4;
  if (i < MN) {
    *(float4*)(out + i) = *(const float4*)(bias + (i % N));
  }
}

struct Pf {
  float4 a0, a1;   // 8 fp32 of x
  int w0, w1;      // 2 packed qweight words
  unsigned zrep;   // fp16(1025+z) replicated in both halves
  unsigned srep;   // fp16(s) replicated
};

__global__ __launch_bounds__(512, 2) void qgemm_kernel(
    const float* __restrict__ x, const int* __restrict__ qw,
    const int* __restrict__ qz, const float* __restrict__ sc,
    float* __restrict__ out, int M, int N, int K) {
  __shared__ __align__(16) unsigned char smem[2 * LDS_HALF];  // 48 KB
  const int tid = threadIdx.x;
  const int n0 = blockIdx.x * BN;
  const int m0 = blockIdx.y * BM;
  const int KC = K / SPLITK;
  const int kbase = blockIdx.z * KC;
  const int nt = KC / BK;              // 8, even
  const int wid = tid >> 6;
  const int lane = tid & 63;
  const int wr = wid >> 2;   // 0..1
  const int wc = wid & 3;    // 0..3
  const int lcol = lane & 15;
  const int lk = lane >> 4;
  const int N8 = N >> 3;

  f32x4 acc[2][2] = {};

  // A staging map: thread -> (row 0..63, col-group 0..7), 8 fp32
  const int arow = tid >> 3;
  const int acg = tid & 7;
  // B staging map: thread -> (col 0..127, packed rows {r, r+4}), r = tid>>7
  const int bcol = tid & 127;
  const int brow8 = tid >> 7;   // 0..3
  const int gn = n0 + bcol;

  auto LOAD = [&](int t, Pf& p) {
    int k0 = kbase + t * BK;
    const float* src = x + (m0 + arow) * K + k0 + acg * 8;
    p.a0 = *(const float4*)(src);
    p.a1 = *(const float4*)(src + 4);
    int g = k0 >> 7;
    int kq0 = k0 >> 3;
    p.w0 = qw[(kq0 + brow8) * N + gn];
    p.w1 = qw[(kq0 + brow8 + 4) * N + gn];
    int zv = (qz[g * N8 + (gn >> 3)] >> ((bcol & 7) * 4)) & 0xF;
    p.zrep = (0x6400u + (unsigned)zv + 1u) * 0x00010001u;  // fp16(1025+z) x2
    float s = sc[g * N + gn];
    p.srep = pkrtz(s, s);
  };

  // k-order inside each 16B unit (both A and B): [0,4,1,5,2,6,3,7]
  auto STORE = [&](int buf, const Pf& p) {
    unsigned char* base = smem + buf * LDS_HALF;
    // A: fp32 -> packed fp16 pairs (x[j], x[j+4])
    uint4 aw;
    aw.x = pkrtz(p.a0.x, p.a1.x);
    aw.y = pkrtz(p.a0.y, p.a1.y);
    aw.z = pkrtz(p.a0.z, p.a1.z);
    aw.w = pkrtz(p.a0.w, p.a1.w);
    *(uint4*)(base + arow * 128 + ((acg ^ (arow & 7)) << 4)) = aw;

    // B: int4 -> fp16 via 0x6400 trick, exact sub then one mul rounding
    unsigned char* bb = base + 8192;
    half2v zh = __builtin_bit_cast(half2v, p.zrep);
    half2v sh = __builtin_bit_cast(half2v, p.srep);
    uint4 b0, b1;
    unsigned v0 = (unsigned)p.w0, v1 = (unsigned)p.w1;
#pragma unroll
    for (int b = 0; b < 4; ++b) {
      unsigned t0 = ((v0 >> (4 * b)) & 0x000F000Fu) | 0x64006400u;
      unsigned t1 = ((v1 >> (4 * b)) & 0x000F000Fu) | 0x64006400u;
      half2v h0 = (__builtin_bit_cast(half2v, t0) - zh) * sh;
      half2v h1 = (__builtin_bit_cast(half2v, t1) - zh) * sh;
      (&b0.x)[b] = __builtin_bit_cast(unsigned, h0);
      (&b1.x)[b] = __builtin_bit_cast(unsigned, h1);
    }
    *(uint4*)(bb + bcol * 128 + ((brow8 ^ (bcol & 7)) << 4)) = b0;
    *(uint4*)(bb + bcol * 128 + (((brow8 + 4) ^ (bcol & 7)) << 4)) = b1;
  };

  auto COMPUTE = [&](int buf) {
    unsigned char* base = smem + buf * LDS_HALF;
    unsigned char* bb = base + 8192;
#pragma unroll
    for (int kk = 0; kk < 2; ++kk) {
      half8 a[2], b[2];
      int unit = kk * 4 + lk;
#pragma unroll
      for (int fi = 0; fi < 2; ++fi) {
        int row = wr * 32 + fi * 16 + lcol;
        a[fi] = *(half8*)(base + row * 128 + ((unit ^ (row & 7)) << 4));
      }
#pragma unroll
      for (int fj = 0; fj < 2; ++fj) {
        int nrow = wc * 32 + fj * 16 + lcol;
        b[fj] = *(half8*)(bb + nrow * 128 + ((unit ^ (nrow & 7)) << 4));
      }
#pragma unroll
      for (int fi = 0; fi < 2; ++fi)
#pragma unroll
        for (int fj = 0; fj < 2; ++fj)
          acc[fi][fj] = __builtin_amdgcn_mfma_f32_16x16x32_f16(
              a[fi], b[fj], acc[fi][fj], 0, 0, 0);
    }
  };

  // 2-deep pipeline, two named prefetch slots (static indexing)
  Pf sA, sB;
  LOAD(0, sA);
  STORE(0, sA);
  LOAD(1, sB);
  __syncthreads();

  for (int t = 0; t < nt; t += 2) {
    if (t + 2 < nt) LOAD(t + 2, sA);
    COMPUTE(0);
    STORE(1, sB);              // tile t+1 (loaded one full iter ago)
    __syncthreads();

    if (t + 3 < nt) LOAD(t + 3, sB);
    COMPUTE(1);
    if (t + 2 < nt) STORE(0, sA);
    __syncthreads();
  }

  // epilogue: atomic-accumulate split-K partials (bias pre-written by init)
#pragma unroll
  for (int fi = 0; fi < 2; ++fi) {
    int gm = m0 + wr * 32 + fi * 16 + lk * 4;
#pragma unroll
    for (int fj = 0; fj < 2; ++fj) {
      int gc = n0 + wc * 32 + fj * 16 + lcol;
#pragma unroll
      for (int r = 0; r < 4; ++r)
        unsafeAtomicAdd(&out[(gm + r) * N + gc], acc[fi][fj][r]);
    }
  }
}

extern "C" void kernel_launch(void* const* d_in, const int* in_sizes, int n_in,
                              void* d_out, int out_size, void* d_ws, size_t ws_size,
                              hipStream_t stream) {
  const float* x = (const float*)d_in[0];
  const int* qw = (const int*)d_in[1];
  const int* qz = (const int*)d_in[2];
  const float* sc = (const float*)d_in[3];
  const float* bias = (const float*)d_in[4];
  float* out = (float*)d_out;

  int N = in_sizes[4];
  int K = (in_sizes[1] / N) * 8;
  int M = in_sizes[0] / K;
  int MN = M * N;

  init_out_kernel<<<(MN / 4 + 255) / 256, 256, 0, stream>>>(bias, out, MN, N);

  dim3 grid(N / BN, M / BM, SPLITK);
  qgemm_kernel<<<grid, 512, 0, stream>>>(x, qw, qz, sc, out, M, N, K);
}